// Round 8
// baseline (81.275 us; speedup 1.0000x reference)
//
#include <hip/hip_runtime.h>
#include <hip/hip_bf16.h>
#include <math.h>

#define NN 55
#define KK 8192
#define OO 8192

using bf16x8 = __attribute__((ext_vector_type(8))) __bf16;
using f32x4  = __attribute__((ext_vector_type(4))) float;

__device__ inline bf16x8 cvt8(f32x4 lo, f32x4 hi) {
    bf16x8 v;
    v[0] = (__bf16)lo[0]; v[1] = (__bf16)lo[1];
    v[2] = (__bf16)lo[2]; v[3] = (__bf16)lo[3];
    v[4] = (__bf16)hi[0]; v[5] = (__bf16)hi[1];
    v[6] = (__bf16)hi[2]; v[7] = (__bf16)hi[3];
    return v;
}

// Kernel 1: x [55,8192] f32 -> xb [64,8192] bf16, rows 55..63 zeroed.
__global__ __launch_bounds__(256)
void cvt_x(const float* __restrict__ xg, __bf16* __restrict__ xb) {
    const int idx = blockIdx.x * 256 + threadIdx.x;
    const int row = idx >> 10;
    const int c8  = (idx & 1023) * 8;
    bf16x8 v = {};
    if (row < NN) {
        const float* p = xg + (size_t)row * KK + c8;
        v = cvt8(*(const f32x4*)p, *(const f32x4*)(p + 4));
    }
    *(bf16x8*)(xb + (size_t)row * KK + c8) = v;
}

__device__ inline void gll16(const float* src, float* dstLds) {
    __builtin_amdgcn_global_load_lds(
        (const __attribute__((address_space(1))) void*)src,
        (__attribute__((address_space(3))) void*)dstLds, 16, 0, 0);
}

#define WAITVM(N) asm volatile("s_waitcnt vmcnt(" #N ")" ::: "memory")

// Kernel 2: out = elu(x @ W^T + b).  BARRIER-FREE per-wave pipeline.
// 256 blocks x 256 threads (4 waves). Wave w = (ow = w>>1, kw = w&1):
// o-cols [obase + ow*16, +16), K-range [kw*4096, +4096). 64 compute-lines
// of k=64; W staged per-wave into PRIVATE LDS (32KB/wave: 2 bufs x 16 rows
// x 1KB -- same 1KB/row granule as R3) in super-stages of k=256, each
// issued as two 8-gll16 halves on lines 0,1 of the preceding super-stage.
// No s_barrier in the loop: each wave self-paces on counted vmcnt
// (mod-4 pattern 8/16/16/8; every forced completion has >=2-line cover).
// A (bf16 xb, L2-resident) register-prefetched 2 lines ahead, 2 slots.
// One __syncthreads() pair for the cross-wave kw-reduction at the end.
__global__ __launch_bounds__(256, 1)
void gat_gemm_elu8(const __bf16* __restrict__ xb,
                   const float* __restrict__ wg,
                   const float* __restrict__ bg,
                   float* __restrict__ outg) {
    __shared__ float Wbuf[32768];   // 128 KiB = 4 waves x 2 bufs x 16KB

    const int tid  = threadIdx.x;
    const int lane = tid & 63;
    const int w    = tid >> 6;      // 0..3
    const int ow   = w >> 1;        // o-group
    const int kw   = w & 1;         // k-half
    const int r    = lane & 15;
    const int q    = lane >> 4;
    const int obase = blockIdx.x * 32;

    // W global base for this wave (wave-uniform) + per-lane xor'd chunk offsets
    const char* wbase = (const char*)(wg + (size_t)(obase + ow * 16) * KK + kw * 4096);
    int lofs[8];
#pragma unroll
    for (int e = 0; e < 8; ++e) lofs[e] = (lane ^ e) << 4;   // byte offset of 16B chunk

    char* wch = (char*)Wbuf + w * 32768 / 1;  // bytes; wave region
    // NOTE: w*32768 bytes would exceed; region is 32KB = 32768 bytes per wave:
    wch = (char*)Wbuf + (size_t)w * 32768;

    const __bf16* abase = xb + (size_t)r * KK + kw * 4096 + q * 8;

    const int roff = r * 1024;                      // LDS row stride (1KB/row)
    const int x0   = ((q * 2)     ^ (r & 7)) << 4;  // swizzled 16B chunk, h=0
    const int x1   = ((q * 2 + 1) ^ (r & 7)) << 4;  // swizzled 16B chunk, h=1

    f32x4 acc[4] = {};
    bf16x8 A0[8], A1[8];   // [mt*2+ks], 2-line ping-pong

// stage 8 rows (HALF*8 .. +7) of super-stage SIG into buf BUF (8 gll16, 1KB/row)
#define WHALF(BUF, SIG, HALF) do {                                           \
    _Pragma("unroll")                                                        \
    for (int jj = 0; jj < 8; ++jj) {                                         \
        const int lr = (HALF) * 8 + jj;                                      \
        gll16((const float*)(wbase + (size_t)lr * (KK * 4) + (SIG) * 1024    \
                             + lofs[jj]),                                    \
              (float*)(wch + (BUF) * 16384 + lr * 1024));                    \
    } } while (0)

#define LOADA(SL, S) do {                                                    \
    const __bf16* a_ = abase + (S) * 64;                                     \
    _Pragma("unroll")                                                        \
    for (int mt = 0; mt < 4; ++mt) {                                         \
        _Pragma("unroll")                                                    \
        for (int ks = 0; ks < 2; ++ks) {                                     \
            SL[mt * 2 + ks] =                                                \
                *(const bf16x8*)(a_ + (size_t)mt * 16 * KK + ks * 32);       \
        }                                                                    \
    } } while (0)

#define COMP(BUF, SUB, AS) do {                                              \
    const char* wb_ = wch + (BUF) * 16384 + roff + (SUB) * 256;              \
    _Pragma("unroll")                                                        \
    for (int ks = 0; ks < 2; ++ks) {                                         \
        const f32x4 lo = *(const f32x4*)(wb_ + ks * 128 + x0);               \
        const f32x4 hi = *(const f32x4*)(wb_ + ks * 128 + x1);               \
        const bf16x8 b0 = cvt8(lo, hi);                                      \
        acc[0] = __builtin_amdgcn_mfma_f32_16x16x32_bf16(AS[0 * 2 + ks], b0, acc[0], 0, 0, 0); \
        acc[1] = __builtin_amdgcn_mfma_f32_16x16x32_bf16(AS[1 * 2 + ks], b0, acc[1], 0, 0, 0); \
        acc[2] = __builtin_amdgcn_mfma_f32_16x16x32_bf16(AS[2 * 2 + ks], b0, acc[2], 0, 0, 0); \
        acc[3] = __builtin_amdgcn_mfma_f32_16x16x32_bf16(AS[3 * 2 + ks], b0, acc[3], 0, 0, 0); \
    } } while (0)

    // prologue: super-stage 0 (full, 16 gll16) + A0, A1  -> queue [W16, A8, A8]
    WHALF(0, 0, 0); WHALF(0, 0, 1);
    LOADA(A0, 0); LOADA(A1, 1);

    // groups g = 0..14: lines 4g..4g+3 compute buf (g&1) = super-stage g,
    // while staging super-stage g+1 into buf (g&1)^1 on the first two lines.
#pragma unroll 1
    for (int g = 0; g < 15; ++g) {
        const int s  = g * 4;
        const int cb = g & 1;
        const int nb = cb ^ 1;
        WAITVM(8);  COMP(cb, 0, A0); WHALF(nb, g + 1, 0); LOADA(A0, s + 2);
        WAITVM(16); COMP(cb, 1, A1); WHALF(nb, g + 1, 1); LOADA(A1, s + 3);
        WAITVM(16); COMP(cb, 2, A0);                      LOADA(A0, s + 4);
        WAITVM(8);  COMP(cb, 3, A1);                      LOADA(A1, s + 5);
    }
    // tail: g = 15, lines 60..63, buf 1, no more staging
    WAITVM(8); COMP(1, 0, A0); LOADA(A0, 62);
    WAITVM(8); COMP(1, 1, A1); LOADA(A1, 63);
    WAITVM(8); COMP(1, 2, A0);
    WAITVM(0); COMP(1, 3, A1);

    // cross-wave kw-reduction. red region = first 16KB of LDS (aliases wave
    // 0's bufs) -> must barrier before writing.
    __syncthreads();
    float* red = Wbuf;   // red[w][row 0..63][col 0..15]
#pragma unroll
    for (int mt = 0; mt < 4; ++mt) {
#pragma unroll
        for (int e = 0; e < 4; ++e) {
            const int row = mt * 16 + q * 4 + e;
            red[w * 1024 + row * 16 + r] = acc[mt][e];
        }
    }
    __syncthreads();

    // 2048 outputs (2 o-groups x 64 rows x 16 cols), 8 per thread
#pragma unroll
    for (int t = 0; t < 8; ++t) {
        const int i   = tid + t * 256;
        const int og  = i >> 10;
        const int row = (i >> 4) & 63;
        const int col = i & 15;
        const float ssum = red[(og * 2 + 0) * 1024 + row * 16 + col]
                         + red[(og * 2 + 1) * 1024 + row * 16 + col];
        const float v   = ssum + bg[obase + og * 16 + col];
        const float res = (v > 0.f) ? v : expm1f(v);
        if (row < NN) outg[(size_t)row * OO + obase + og * 16 + col] = res;
    }
#undef WHALF
#undef LOADA
#undef COMP
}

extern "C" void kernel_launch(void* const* d_in, const int* in_sizes, int n_in,
                              void* d_out, int out_size, void* d_ws, size_t ws_size,
                              hipStream_t stream) {
    const float* x  = (const float*)d_in[0];
    const float* W1 = (const float*)d_in[3];
    const float* b1 = (const float*)d_in[4];
    float* out = (float*)d_out;
    __bf16* xb = (__bf16*)d_ws;   // 64*8192*2 = 1 MB

    cvt_x<<<dim3(256), dim3(256), 0, stream>>>(x, xb);
    gat_gemm_elu8<<<dim3(OO / 32), dim3(256), 0, stream>>>(xb, W1, b1, out);
}

// Round 9
// 74.146 us; speedup vs baseline: 1.0962x; 1.0962x over previous
//
#include <hip/hip_runtime.h>
#include <hip/hip_bf16.h>
#include <math.h>

#define NN 55
#define KK 8192
#define OO 8192

using bf16x8 = __attribute__((ext_vector_type(8))) __bf16;
using f32x4  = __attribute__((ext_vector_type(4))) float;

__device__ inline bf16x8 cvt8(f32x4 lo, f32x4 hi) {
    bf16x8 v;
    v[0] = (__bf16)lo[0]; v[1] = (__bf16)lo[1];
    v[2] = (__bf16)lo[2]; v[3] = (__bf16)lo[3];
    v[4] = (__bf16)hi[0]; v[5] = (__bf16)hi[1];
    v[6] = (__bf16)hi[2]; v[7] = (__bf16)hi[3];
    return v;
}

// W staging: default cache policy (aux=0); NT costs ~6us of L3 retention (R6).
__device__ inline void gll16(const float* src, float* dstLds) {
    __builtin_amdgcn_global_load_lds(
        (const __attribute__((address_space(1))) void*)src,
        (__attribute__((address_space(3))) void*)dstLds, 16, 0, 0);
}

#define WAITVM(N) asm volatile("s_waitcnt vmcnt(" #N ")" ::: "memory")
#define BAR() __builtin_amdgcn_s_barrier()

// out = elu(x @ W^T + b)  -- single kernel (cvt_x folded in: A loaded f32,
// converted to bf16 at compute time; rows 55..63 address-clamped to row 54,
// results finite and never stored).
// 256 blocks x 512 threads (8 waves), o-tile 32 W-rows, 1 block/CU.
// K in 32 stages of 256; line s: WAITVM(24); BAR; STAGE_W(s+3); LOAD_A(s+3);
// COMPUTE(s). 4 LDS bufs x 32KB = 128KB. Window = 12 VMEM/line (4 gll16 +
// 8 A-f32x4) -> steady vmcnt(24) = 2 windows. Wave w computes k-slice
// [w*32, w*32+32) per stage; A slots hold raw f32 (cvt deferred to COMPUTE
// so no early vmcnt dependency).
__global__ __launch_bounds__(512, 2)
void gat_gemm_elu9(const float* __restrict__ xg,
                   const float* __restrict__ wg,
                   const float* __restrict__ bg,
                   float* __restrict__ outg) {
    __shared__ float Wbuf[4 * 8192];   // 128 KiB: 4 bufs x (32 rows x 256 f32)

    const int tid  = threadIdx.x;
    const int lane = tid & 63;
    const int w    = tid >> 6;
    const int r    = lane & 15;
    const int q    = lane >> 4;
    const int w4   = w * 4;
    const int obase = blockIdx.x * 32;

    // Wave stages rows lr = 4w..4w+3. LDS 16B-chunk c holds global chunk
    // c^(lr&7) (involution within each row's 1KB).
    const float* wsrc[4];
#pragma unroll
    for (int j = 0; j < 4; ++j) {
        const int lr = w4 + j;
        wsrc[j] = wg + (size_t)(obase + lr) * KK + ((lane ^ (lr & 7)) << 2);
    }

    // A bases per m-tile, row clamped to 54 (rows 55..63 load duplicated
    // finite data; their acc rows are never stored).
    const float* aptr[4];
#pragma unroll
    for (int mt = 0; mt < 4; ++mt) {
        int arow = mt * 16 + r;
        if (arow > NN - 1) arow = NN - 1;
        aptr[mt] = xg + (size_t)arow * KK + w * 32 + q * 8;
    }

    const int sw  = (r & 7) << 4;
    const int kx0 = (w * 128 + q * 32) ^ sw;
    const int kx1 = (w * 128 + q * 32 + 16) ^ sw;

    f32x4 acc0[4] = {};
    f32x4 acc1[4] = {};
    f32x4 A0[8], A1[8], A2[8], A3[8];   // [2*mt], [2*mt+1]: raw f32 frags

#define STAGE_W(BUF, STG) do {                                              \
    const int kb_ = (STG) * 256;                                            \
    _Pragma("unroll")                                                       \
    for (int j = 0; j < 4; ++j) {                                           \
        gll16(wsrc[j] + kb_, &Wbuf[(BUF) * 8192 + (w4 + j) * 256]);         \
    } } while (0)

#define LOAD_A(SLOT, STG) do {                                              \
    const int ko_ = (STG) * 256;                                            \
    _Pragma("unroll")                                                       \
    for (int mt = 0; mt < 4; ++mt) {                                        \
        SLOT[2 * mt]     = *(const f32x4*)(aptr[mt] + ko_);                 \
        SLOT[2 * mt + 1] = *(const f32x4*)(aptr[mt] + ko_ + 4);             \
    } } while (0)

#define COMPUTE(BUF, AS) do {                                               \
    const char* wb_ = (const char*)&Wbuf[(BUF) * 8192];                     \
    const f32x4 lo0 = *(const f32x4*)(wb_ + r * 1024 + kx0);                \
    const f32x4 hi0 = *(const f32x4*)(wb_ + r * 1024 + kx1);                \
    const f32x4 lo1 = *(const f32x4*)(wb_ + (16 + r) * 1024 + kx0);         \
    const f32x4 hi1 = *(const f32x4*)(wb_ + (16 + r) * 1024 + kx1);         \
    const bf16x8 b0 = cvt8(lo0, hi0);                                       \
    const bf16x8 b1 = cvt8(lo1, hi1);                                       \
    _Pragma("unroll")                                                       \
    for (int mt = 0; mt < 4; ++mt) {                                        \
        const bf16x8 af = cvt8(AS[2 * mt], AS[2 * mt + 1]);                 \
        acc0[mt] = __builtin_amdgcn_mfma_f32_16x16x32_bf16(af, b0, acc0[mt], 0, 0, 0); \
        acc1[mt] = __builtin_amdgcn_mfma_f32_16x16x32_bf16(af, b1, acc1[mt], 0, 0, 0); \
    } } while (0)

    // prologue: 3 stage-windows in flight (36 VMEM)
    STAGE_W(0, 0); LOAD_A(A0, 0);
    STAGE_W(1, 1); LOAD_A(A1, 1);
    STAGE_W(2, 2); LOAD_A(A2, 2);

    // main: lines 0..27 in 7 groups of 4 (static buf/slot indices)
#pragma unroll 1
    for (int su = 0; su < 7; ++su) {
        const int s = su * 4;
        WAITVM(24); BAR(); STAGE_W(3, s + 3); LOAD_A(A3, s + 3); COMPUTE(0, A0);
        WAITVM(24); BAR(); STAGE_W(0, s + 4); LOAD_A(A0, s + 4); COMPUTE(1, A1);
        WAITVM(24); BAR(); STAGE_W(1, s + 5); LOAD_A(A1, s + 5); COMPUTE(2, A2);
        WAITVM(24); BAR(); STAGE_W(2, s + 6); LOAD_A(A2, s + 6); COMPUTE(3, A3);
    }
    // lines 28..31
    WAITVM(24); BAR(); STAGE_W(3, 31); LOAD_A(A3, 31); COMPUTE(0, A0);
    WAITVM(24); BAR(); COMPUTE(1, A1);
    WAITVM(12); BAR(); COMPUTE(2, A2);
    WAITVM(0);  BAR(); COMPUTE(3, A3);

    // cross-wave reduce in bufs 0-1 (64KB). After the final BAR, every wave
    // has passed line 30; remaining reads touch only buf 3 (stage 31), and
    // bufs 0-1 were last read at lines 28/29 (before barriers all crossed).
    float* red = Wbuf;
#pragma unroll
    for (int mt = 0; mt < 4; ++mt) {
#pragma unroll
        for (int e = 0; e < 4; ++e) {
            const int row = mt * 16 + q * 4 + e;
            red[w * 2048 + row * 32 + r]      = acc0[mt][e];
            red[w * 2048 + row * 32 + 16 + r] = acc1[mt][e];
        }
    }
    __syncthreads();

    for (int i = tid; i < 2048; i += 512) {
        float ssum = 0.f;
#pragma unroll
        for (int ww = 0; ww < 8; ++ww) ssum += red[ww * 2048 + i];
        const int row = i >> 5;
        const int col = i & 31;
        const float v = ssum + bg[obase + col];
        const float res = (v > 0.f) ? v : expm1f(v);
        if (row < NN) outg[(size_t)row * OO + obase + col] = res;
    }
#undef STAGE_W
#undef LOAD_A
#undef COMPUTE
}

extern "C" void kernel_launch(void* const* d_in, const int* in_sizes, int n_in,
                              void* d_out, int out_size, void* d_ws, size_t ws_size,
                              hipStream_t stream) {
    const float* x  = (const float*)d_in[0];
    const float* W1 = (const float*)d_in[3];
    const float* b1 = (const float*)d_in[4];
    float* out = (float*)d_out;

    gat_gemm_elu9<<<dim3(OO / 32), dim3(512), 0, stream>>>(x, W1, b1, out);
}